// Round 3
// baseline (170.999 us; speedup 1.0000x reference)
//
#include <hip/hip_runtime.h>
#include <hip/hip_bf16.h>
#include <cstdint>
#include <cstddef>

// SetConvDecoder on MI355X (gfx950).
// out[b,t,c] = (1/128) * sum_g exp(-0.5*||(xt[b,t]-xg[b,g])/ls||^2) * zg[b,g,c]
// B=4, NT=2048, NG=16384, DZ=128, DX=2.
//
// Round-3:
//  - pre_kernel: vectorized f32->bf16 (*1/128) with LDS transpose into the
//    MFMA B-fragment tile layout; xg/xt scaled triplets.
//  - main_kernel: 1024 blocks x 128 thr (2 waves = rh pair sharing one zg
//    tile). Sync domain = 2 waves only; 4 independent blocks/CU fill stalls.
//    Ring-3 LDS, prefetch distance 2, counted vmcnt(2) (never 0 mid-loop).
//    Triplets staged once to LDS (no per-tile global traffic). Weights in
//    registers (2 fma + add + v_exp each), mfma_f32_32x32x16_bf16.
//    Epilogue: direct f32 atomicAdd into memset-zeroed out (16 K-chunks).

typedef float  f32x4  __attribute__((ext_vector_type(4)));
typedef float  f32x16 __attribute__((ext_vector_type(16)));
typedef short  short8 __attribute__((ext_vector_type(8)));
typedef unsigned short ushort4v __attribute__((ext_vector_type(4)));
typedef unsigned short ushort8 __attribute__((ext_vector_type(8)));

#if __has_builtin(__builtin_amdgcn_exp2f)
#define EXP2F(x) __builtin_amdgcn_exp2f(x)
#else
#define EXP2F(x) exp2f(x)
#endif

#define AS1C(p) ((const __attribute__((address_space(1))) void*)(p))
#define AS3(p)  ((__attribute__((address_space(3))) void*)(p))

__device__ __forceinline__ unsigned short bf16_bits(float f) {
  __bf16 h = (__bf16)f;
  return __builtin_bit_cast(unsigned short, h);
}

// ---------------------------------------------------------------------------
// Pre-kernel: 1024 blocks (b4 x 256 groups of 64 g-rows) x 256 threads.
// Phase 1: coalesced float4 reads of z_grid, *1/128, bf16, to LDS [64][128].
// Phase 2: transpose-gather 8 k's per (q2,c), contiguous ushort8 writes in
// the per-16k-tile fragment layout: elem (q2*128+c)*8 + hi*4 + j holds
// k16 = 4*q2 + 8*hi + j.
// Triplets: xg (2u0, 2u1, -|u|^2) 12B/g; xt (u0,u1,-|u|^2,0) 16B/row;
// u = x * sqrt(0.5*log2 e) / ls.
// ---------------------------------------------------------------------------
__global__ __launch_bounds__(256) void pre_kernel(
    const float* __restrict__ x_grid, const float* __restrict__ z_grid,
    const float* __restrict__ xt, const float* __restrict__ lsp,
    unsigned short* __restrict__ zgb, float* __restrict__ xg_trip,
    float* __restrict__ xt4)
{
  __shared__ unsigned short lt[64 * 128];   // 16 KB row-major [row][c]
  const int bid = blockIdx.x;
  const int b   = bid >> 8;
  const int grp = bid & 255;
  const int tid = threadIdx.x;
  const size_t gbase = (size_t)b * 16384 + grp * 64;
  const float sc = 1.0f / 128.0f;

  const float* zr = z_grid + gbase * 128;
  #pragma unroll
  for (int it = 0; it < 8; ++it) {
    const int idx = it * 256 + tid;
    const int row = idx >> 5, c4 = idx & 31;
    f32x4 v = *(const f32x4*)(zr + row * 128 + c4 * 4);
    ushort4v o;
    o.x = bf16_bits(v.x * sc); o.y = bf16_bits(v.y * sc);
    o.z = bf16_bits(v.z * sc); o.w = bf16_bits(v.w * sc);
    *(ushort4v*)(lt + row * 128 + c4 * 4) = o;
  }

  // triplets (no LDS dependency)
  if (tid < 128) {
    const float ls0 = 1e-5f + log1pf(expf(lsp[0]));
    const float ls1 = 1e-5f + log1pf(expf(lsp[1]));
    const float cs  = sqrtf(0.7213475204444817f);   // sqrt(0.5*log2 e)
    const float s0 = cs / ls0, s1 = cs / ls1;
    if (tid < 64) {
      const size_t g = gbase + tid;
      const float u0 = x_grid[g * 2 + 0] * s0;
      const float u1 = x_grid[g * 2 + 1] * s1;
      float* d = xg_trip + g * 3;
      d[0] = 2.0f * u0; d[1] = 2.0f * u1; d[2] = -(u0 * u0 + u1 * u1);
    } else if (bid < 128) {
      const int bx = bid >> 5;
      const int r  = (bid & 31) * 64 + (tid - 64);
      const float u0 = xt[((size_t)(bx * 2048 + r)) * 2 + 0] * s0;
      const float u1 = xt[((size_t)(bx * 2048 + r)) * 2 + 1] * s1;
      f32x4 d; d.x = u0; d.y = u1; d.z = -(u0 * u0 + u1 * u1); d.w = 0.0f;
      *(f32x4*)(xt4 + ((size_t)(bx * 2048 + r)) * 4) = d;
    }
  }

  __syncthreads();

  const int q2p = tid >> 7, c = tid & 127;
  #pragma unroll
  for (int h = 0; h < 4; ++h) {            // 4 16-k tiles per block
    ushort8 o;
    #pragma unroll
    for (int hi = 0; hi < 2; ++hi)
      #pragma unroll
      for (int j = 0; j < 4; ++j)
        o[hi * 4 + j] = lt[(h * 16 + 4 * q2p + 8 * hi + j) * 128 + c];
    *(ushort8*)(zgb + ((size_t)(b * 1024 + grp * 4 + h)) * 2048
                    + (size_t)(q2p * 128 + c) * 8) = o;
  }
}

// ---------------------------------------------------------------------------
// Main kernel: 1024 blocks (XCD-swizzled; lid = ksp16 | b4 | mt16), 128 thr.
// LDS: ring 3 x 4 KB zg tiles + 12 KB triplets = 24 KB -> 4 blocks/CU.
// ---------------------------------------------------------------------------
__global__ __launch_bounds__(128, 2) void main_kernel(
    const unsigned short* __restrict__ zgb,
    const float* __restrict__ xg_trip,
    const float* __restrict__ xt4,
    float* __restrict__ out)
{
  __shared__ __align__(128) char smem[12288 + 12288];
  char* ring = smem;
  char* trip = smem + 12288;

  const int raw = blockIdx.x;
  const int lid = (raw & 7) * 128 + (raw >> 3);   // bijective XCD swizzle
  const int mt  = lid & 15;
  const int b   = (lid >> 4) & 3;
  const int ksp = lid >> 6;                       // 0..15

  const int tid = threadIdx.x;
  const int rh  = tid >> 6;
  const int l   = tid & 63;
  const int l31 = l & 31;
  const int q2  = l >> 5;

  float at0[2], at1[2], ca[2];
  #pragma unroll
  for (int mi = 0; mi < 2; ++mi) {
    const int r = mt * 128 + rh * 64 + mi * 32 + l31;
    f32x4 v = *(const f32x4*)(xt4 + ((size_t)(b * 2048 + r)) * 4);
    at0[mi] = v.x; at1[mi] = v.y; ca[mi] = v.z;
  }

  f32x16 acc[2][4];
  #pragma unroll
  for (int mi = 0; mi < 2; ++mi)
    #pragma unroll
    for (int ni = 0; ni < 4; ++ni)
      #pragma unroll
      for (int e = 0; e < 16; ++e)
        acc[mi][ni][e] = 0.0f;

  const char* zsrc = (const char*)zgb + ((size_t)(b * 1024 + ksp * 64)) * 4096;
  const char* tsrc = (const char*)xg_trip + ((size_t)(b * 16384 + ksp * 1024)) * 12;

  auto stage = [&](int s) {                 // 2 gl_lds per wave (its half)
    const char* zs = zsrc + (size_t)s * 4096 + rh * 2048;
    char* zd = ring + (s % 3) * 4096 + rh * 2048;
    __builtin_amdgcn_global_load_lds(AS1C(zs + l * 16), AS3(zd + l * 16), 16, 0, 0);
    __builtin_amdgcn_global_load_lds(AS1C(zs + 1024 + l * 16),
                                     AS3(zd + 1024 + l * 16), 16, 0, 0);
  };

  // prologue: 6 triplet loads (12 KB across the pair), then tiles 0,1
  #pragma unroll
  for (int w = 0; w < 6; ++w) {
    const int off = (rh * 6 + w) * 1024 + l * 16;
    __builtin_amdgcn_global_load_lds(AS1C(tsrc + off), AS3(trip + off), 16, 0, 0);
  }
  stage(0);
  stage(1);

  for (int s = 0; s < 64; ++s) {
    // drain tile s (and, at s=0, the triplets); keep later stages in flight
    if (s < 63) { asm volatile("s_waitcnt vmcnt(2)" ::: "memory"); }
    else        { asm volatile("s_waitcnt vmcnt(0)" ::: "memory"); }
    __builtin_amdgcn_s_barrier();           // 2-wave rendezvous
    asm volatile("" ::: "memory");

    if (s + 2 < 64) stage(s + 2);           // slot (s+2)%3 last read at s-1

    // xg triplets for this lane's 8 k's (broadcast within 32-lane half)
    const float* tb = (const float*)(trip + s * 192 + q2 * 48);
    f32x4 L0 = *(const f32x4*)(tb + 0);
    f32x4 L1 = *(const f32x4*)(tb + 4);
    f32x4 L2 = *(const f32x4*)(tb + 8);
    f32x4 H0 = *(const f32x4*)(tb + 24);
    f32x4 H1 = *(const f32x4*)(tb + 28);
    f32x4 H2 = *(const f32x4*)(tb + 32);
    float g0[8], g1[8], cb[8];
    g0[0]=L0.x; g1[0]=L0.y; cb[0]=L0.z;
    g0[1]=L0.w; g1[1]=L1.x; cb[1]=L1.y;
    g0[2]=L1.z; g1[2]=L1.w; cb[2]=L2.x;
    g0[3]=L2.y; g1[3]=L2.z; cb[3]=L2.w;
    g0[4]=H0.x; g1[4]=H0.y; cb[4]=H0.z;
    g0[5]=H0.w; g1[5]=H1.x; cb[5]=H1.y;
    g0[6]=H1.z; g1[6]=H1.w; cb[6]=H2.x;
    g0[7]=H2.y; g1[7]=H2.z; cb[7]=H2.w;

    // B-fragments: contiguous 16B/lane, conflict-free
    const char* zt = ring + (s % 3) * 4096 + q2 * 2048 + l31 * 16;
    short8 bfr[4];
    #pragma unroll
    for (int ni = 0; ni < 4; ++ni)
      bfr[ni] = *(const short8*)(zt + ni * 512);

    // A-fragments (RBF weights) in registers
    short8 af[2];
    #pragma unroll
    for (int mi = 0; mi < 2; ++mi) {
      union { short8 s8; __bf16 e[8]; } u;
      #pragma unroll
      for (int j = 0; j < 8; ++j) {
        float arg = __builtin_fmaf(at0[mi], g0[j],
                    __builtin_fmaf(at1[mi], g1[j], ca[mi] + cb[j]));
        u.e[j] = (__bf16)EXP2F(arg);
      }
      af[mi] = u.s8;
    }

    #pragma unroll
    for (int mi = 0; mi < 2; ++mi)
      #pragma unroll
      for (int ni = 0; ni < 4; ++ni)
        acc[mi][ni] = __builtin_amdgcn_mfma_f32_32x32x16_bf16(
            af[mi], bfr[ni], acc[mi][ni], 0, 0, 0);
  }

  // epilogue: add this block's K-chunk into out (zg pre-scaled by 1/128)
  #pragma unroll
  for (int mi = 0; mi < 2; ++mi)
    #pragma unroll
    for (int ni = 0; ni < 4; ++ni)
      #pragma unroll
      for (int r = 0; r < 16; ++r) {
        const int row = mt * 128 + rh * 64 + mi * 32
                      + (r & 3) + 8 * (r >> 2) + 4 * q2;   // verified C/D map
        atomicAdd(out + ((size_t)b * 2048 + row) * 128 + ni * 32 + l31,
                  acc[mi][ni][r]);
      }
}

// ---------------------------------------------------------------------------
extern "C" void kernel_launch(void* const* d_in, const int* in_sizes, int n_in,
                              void* d_out, int out_size, void* d_ws, size_t ws_size,
                              hipStream_t stream) {
  const float* x_grid = (const float*)d_in[0];   // (4,128,128,2)
  const float* z_grid = (const float*)d_in[1];   // (4,128,128,128)
  const float* xt     = (const float*)d_in[2];   // (4,2048,2)
  const float* lsp    = (const float*)d_in[3];   // (2,)
  float* out = (float*)d_out;                    // (4,2048,128) f32

  char* ws = (char*)d_ws;                        // ~17.7 MB used
  unsigned short* zgb = (unsigned short*)ws;                   // 16 MB
  float* xg_trip = (float*)(ws + 16777216);                    // 768 KB
  float* xt4     = (float*)(ws + 16777216 + 786432);           // 128 KB

  hipMemsetAsync(d_out, 0, (size_t)out_size * sizeof(float), stream);
  pre_kernel<<<1024, 256, 0, stream>>>(x_grid, z_grid, xt, lsp,
                                       zgb, xg_trip, xt4);
  main_kernel<<<1024, 128, 0, stream>>>(zgb, xg_trip, xt4, out);
}

// Round 7
// 140.760 us; speedup vs baseline: 1.2148x; 1.2148x over previous
//
#include <hip/hip_runtime.h>
#include <hip/hip_bf16.h>
#include <cstdint>
#include <cstddef>

// SetConvDecoder on MI355X (gfx950).
// out[b,t,c] = (1/128) * sum_g exp(-0.5*||(xt[b,t]-xg[b,g])/ls||^2) * zg[b,g,c]
// B=4, NT=2048, NG=16384, DZ=128, DX=2.
//
// Round-7 == Round-5 resubmitted verbatim (three broker timeouts; this
// structure has never run -- need the measurement before changing theory).
//   main: 512 blocks (b4 x mt16 x ksp8) x 256 thr = 4 waves (rh2 x kk2).
//   All waves MFMA-active; ring-3 LDS, counted vmcnt(2), 4-wave barrier.
//   kk-pair reduced IN BLOCK (64KB LDS exchange). Epilogue: plain coalesced
//   fp32 partial stores to ws (8 x 4MB) + reduce kernel -- NO atomics, no
//   memset (guarded on ws_size; falls back to R4 atomic path if ws too small).

typedef float  f32x4  __attribute__((ext_vector_type(4)));
typedef float  f32x16 __attribute__((ext_vector_type(16)));
typedef short  short8 __attribute__((ext_vector_type(8)));
typedef unsigned short ushort4v __attribute__((ext_vector_type(4)));
typedef unsigned short ushort8 __attribute__((ext_vector_type(8)));

#if __has_builtin(__builtin_amdgcn_exp2f)
#define EXP2F(x) __builtin_amdgcn_exp2f(x)
#else
#define EXP2F(x) exp2f(x)
#endif

#define AS1C(p) ((const __attribute__((address_space(1))) void*)(p))
#define AS3(p)  ((__attribute__((address_space(3))) void*)(p))

__device__ __forceinline__ unsigned short bf16_bits(float f) {
  __bf16 h = (__bf16)f;
  return __builtin_bit_cast(unsigned short, h);
}

// ---------------------------------------------------------------------------
// Pre-kernel: 1024 blocks (b4 x 256 groups of 64 g) x 256 threads.
// zg -> bf16*(1/128) in per-16k-tile fragment layout via LDS transpose;
// xg triplets (2u0,2u1,-|u|^2) 12B/g; xt (u0,u1,-|u|^2,0) 16B/row;
// u = x * sqrt(0.5*log2 e) / ls.
// ---------------------------------------------------------------------------
__global__ __launch_bounds__(256) void pre_kernel(
    const float* __restrict__ x_grid, const float* __restrict__ z_grid,
    const float* __restrict__ xt, const float* __restrict__ lsp,
    unsigned short* __restrict__ zgb, float* __restrict__ xg_trip,
    float* __restrict__ xt4)
{
  __shared__ unsigned short lt[64 * 128];   // 16 KB row-major [row][c]
  const int bid = blockIdx.x;
  const int b   = bid >> 8;
  const int grp = bid & 255;
  const int tid = threadIdx.x;
  const size_t gbase = (size_t)b * 16384 + grp * 64;
  const float sc = 1.0f / 128.0f;

  const float* zr = z_grid + gbase * 128;
  #pragma unroll
  for (int it = 0; it < 8; ++it) {
    const int idx = it * 256 + tid;
    const int row = idx >> 5, c4 = idx & 31;
    f32x4 v = *(const f32x4*)(zr + row * 128 + c4 * 4);
    ushort4v o;
    o.x = bf16_bits(v.x * sc); o.y = bf16_bits(v.y * sc);
    o.z = bf16_bits(v.z * sc); o.w = bf16_bits(v.w * sc);
    *(ushort4v*)(lt + row * 128 + c4 * 4) = o;
  }

  if (tid < 128) {
    const float ls0 = 1e-5f + log1pf(expf(lsp[0]));
    const float ls1 = 1e-5f + log1pf(expf(lsp[1]));
    const float cs  = sqrtf(0.7213475204444817f);   // sqrt(0.5*log2 e)
    const float s0 = cs / ls0, s1 = cs / ls1;
    if (tid < 64) {
      const size_t g = gbase + tid;
      const float u0 = x_grid[g * 2 + 0] * s0;
      const float u1 = x_grid[g * 2 + 1] * s1;
      float* d = xg_trip + g * 3;
      d[0] = 2.0f * u0; d[1] = 2.0f * u1; d[2] = -(u0 * u0 + u1 * u1);
    } else if (bid < 128) {
      const int bx = bid >> 5;
      const int r  = (bid & 31) * 64 + (tid - 64);
      const float u0 = xt[((size_t)(bx * 2048 + r)) * 2 + 0] * s0;
      const float u1 = xt[((size_t)(bx * 2048 + r)) * 2 + 1] * s1;
      f32x4 d; d.x = u0; d.y = u1; d.z = -(u0 * u0 + u1 * u1); d.w = 0.0f;
      *(f32x4*)(xt4 + ((size_t)(bx * 2048 + r)) * 4) = d;
    }
  }

  __syncthreads();

  const int q2p = tid >> 7, c = tid & 127;
  #pragma unroll
  for (int h = 0; h < 4; ++h) {            // 4 16-k tiles per block
    ushort8 o;
    #pragma unroll
    for (int hi = 0; hi < 2; ++hi)
      #pragma unroll
      for (int j = 0; j < 4; ++j)
        o[hi * 4 + j] = lt[(h * 16 + 4 * q2p + 8 * hi + j) * 128 + c];
    *(ushort8*)(zgb + ((size_t)(b * 1024 + grp * 4 + h)) * 2048
                    + (size_t)(q2p * 128 + c) * 8) = o;
  }
}

// ---------------------------------------------------------------------------
// Main kernel. LDS (64 KB): loop = ring[3][2kk][4KB] (24576) + trips (24576);
// epilogue reuses all 64 KB as conflict-free exchange planes.
// ---------------------------------------------------------------------------
__global__ __launch_bounds__(256, 2) void main_kernel(
    const unsigned short* __restrict__ zgb,
    const float* __restrict__ xg_trip,
    const float* __restrict__ xt4,
    float* __restrict__ out,
    float* __restrict__ partials)     // nullptr -> atomic fallback
{
  __shared__ __align__(128) char smem[65536];
  char* ring = smem;                  // 24576
  char* trip = smem + 24576;          // 24576

  const int raw = blockIdx.x;
  const int lid = (raw & 7) * 64 + (raw >> 3);    // bijective XCD swizzle
  const int mt  = lid & 15;
  const int b   = (lid >> 4) & 3;
  const int ksp = lid >> 6;                       // 0..7

  const int tid = threadIdx.x;
  const int wv  = tid >> 6;
  const int l   = tid & 63;
  const int rh  = wv & 1;             // row half (64 rows)
  const int kk  = wv >> 1;            // in-block k-split
  const int l31 = l & 31;
  const int q2  = l >> 5;
  const int chunk = ksp * 2 + kk;     // 16 chunks of 64 16k-tiles

  float at0[2], at1[2], ca[2];
  #pragma unroll
  for (int mi = 0; mi < 2; ++mi) {
    const int r = mt * 128 + rh * 64 + mi * 32 + l31;
    f32x4 v = *(const f32x4*)(xt4 + ((size_t)(b * 2048 + r)) * 4);
    at0[mi] = v.x; at1[mi] = v.y; ca[mi] = v.z;
  }

  f32x16 acc[2][4];
  #pragma unroll
  for (int mi = 0; mi < 2; ++mi)
    #pragma unroll
    for (int ni = 0; ni < 4; ++ni)
      #pragma unroll
      for (int e = 0; e < 16; ++e)
        acc[mi][ni][e] = 0.0f;

  const char* zsrc = (const char*)zgb + ((size_t)(b * 1024 + chunk * 64)) * 4096;
  const char* tsrc = (const char*)xg_trip + ((size_t)(b * 16384 + ksp * 2048)) * 12;

  auto stage = [&](int s) {           // each wave: its rh-half of its kk tile
    const char* zs = zsrc + (size_t)s * 4096 + rh * 2048;
    char* zd = ring + (s % 3) * 8192 + kk * 4096 + rh * 2048;
    __builtin_amdgcn_global_load_lds(AS1C(zs + l * 16), AS3(zd + l * 16), 16, 0, 0);
    __builtin_amdgcn_global_load_lds(AS1C(zs + 1024 + l * 16),
                                     AS3(zd + 1024 + l * 16), 16, 0, 0);
  };

  // prologue: 24 KB of triplets (6 x 1KB per wave), then tiles 0,1
  #pragma unroll
  for (int w = 0; w < 6; ++w) {
    const int off = wv * 6144 + w * 1024 + l * 16;
    __builtin_amdgcn_global_load_lds(AS1C(tsrc + off), AS3(trip + off), 16, 0, 0);
  }
  stage(0);
  stage(1);

  #pragma unroll 3
  for (int s = 0; s < 64; ++s) {
    // drain tile s (and at s=0 the triplets); keep stage(s+1) in flight
    if (s < 63) { asm volatile("s_waitcnt vmcnt(2)" ::: "memory"); }
    else        { asm volatile("s_waitcnt vmcnt(0)" ::: "memory"); }
    __builtin_amdgcn_s_barrier();     // 4-wave rendezvous
    asm volatile("" ::: "memory");

    if (s + 2 < 64) stage(s + 2);     // slot (s+2)%3 last read at iter s-1

    // xg triplets for this lane's 8 k's (broadcast within 32-lane half)
    const float* tb = (const float*)(trip + kk * 12288 + s * 192 + q2 * 48);
    f32x4 L0 = *(const f32x4*)(tb + 0);
    f32x4 L1 = *(const f32x4*)(tb + 4);
    f32x4 L2 = *(const f32x4*)(tb + 8);
    f32x4 H0 = *(const f32x4*)(tb + 24);
    f32x4 H1 = *(const f32x4*)(tb + 28);
    f32x4 H2 = *(const f32x4*)(tb + 32);
    float g0[8], g1[8], cb[8];
    g0[0]=L0.x; g1[0]=L0.y; cb[0]=L0.z;
    g0[1]=L0.w; g1[1]=L1.x; cb[1]=L1.y;
    g0[2]=L1.z; g1[2]=L1.w; cb[2]=L2.x;
    g0[3]=L2.y; g1[3]=L2.z; cb[3]=L2.w;
    g0[4]=H0.x; g1[4]=H0.y; cb[4]=H0.z;
    g0[5]=H0.w; g1[5]=H1.x; cb[5]=H1.y;
    g0[6]=H1.z; g1[6]=H1.w; cb[6]=H2.x;
    g0[7]=H2.y; g1[7]=H2.z; cb[7]=H2.w;

    // B-fragments: contiguous 16B/lane, conflict-free
    const char* zt = ring + (s % 3) * 8192 + kk * 4096 + q2 * 2048 + l31 * 16;
    short8 bfr[4];
    #pragma unroll
    for (int ni = 0; ni < 4; ++ni)
      bfr[ni] = *(const short8*)(zt + ni * 512);

    // A-fragments (RBF weights) in registers
    short8 af[2];
    #pragma unroll
    for (int mi = 0; mi < 2; ++mi) {
      union { short8 s8; __bf16 e[8]; } u;
      #pragma unroll
      for (int j = 0; j < 8; ++j) {
        float arg = __builtin_fmaf(at0[mi], g0[j],
                    __builtin_fmaf(at1[mi], g1[j], ca[mi] + cb[j]));
        u.e[j] = (__bf16)EXP2F(arg);
      }
      af[mi] = u.s8;
    }

    #pragma unroll
    for (int mi = 0; mi < 2; ++mi)
      #pragma unroll
      for (int ni = 0; ni < 4; ++ni)
        acc[mi][ni] = __builtin_amdgcn_mfma_f32_32x32x16_bf16(
            af[mi], bfr[ni], acc[mi][ni], 0, 0, 0);
  }

  // ---- in-block kk reduction (one 64KB exchange) ----
  __syncthreads();                    // loop reads done; reuse all of smem
  if (kk == 1) {
    #pragma unroll
    for (int mi = 0; mi < 2; ++mi)
      #pragma unroll
      for (int ni = 0; ni < 4; ++ni)
        #pragma unroll
        for (int q = 0; q < 4; ++q) {
          f32x4 v;
          v.x = acc[mi][ni][q * 4 + 0]; v.y = acc[mi][ni][q * 4 + 1];
          v.z = acc[mi][ni][q * 4 + 2]; v.w = acc[mi][ni][q * 4 + 3];
          *(f32x4*)(smem + rh * 32768 + (mi * 4 + ni) * 4096 + q * 1024 + l * 16) = v;
        }
  }
  __syncthreads();
  if (kk == 0) {
    float* pb = partials ? partials + ((size_t)(ksp * 64 + b * 16 + mt)) * 16384
                         : nullptr;
    #pragma unroll
    for (int mi = 0; mi < 2; ++mi)
      #pragma unroll
      for (int ni = 0; ni < 4; ++ni) {
        #pragma unroll
        for (int q = 0; q < 4; ++q) {
          f32x4 v = *(const f32x4*)(smem + rh * 32768 + (mi * 4 + ni) * 4096
                                         + q * 1024 + l * 16);
          acc[mi][ni][q * 4 + 0] += v.x; acc[mi][ni][q * 4 + 1] += v.y;
          acc[mi][ni][q * 4 + 2] += v.z; acc[mi][ni][q * 4 + 3] += v.w;
        }
        #pragma unroll
        for (int r = 0; r < 16; ++r) {
          const int row = rh * 64 + mi * 32
                        + (r & 3) + 8 * (r >> 2) + 4 * q2;  // verified C/D map
          const int col = ni * 32 + l31;
          if (pb) {
            pb[row * 128 + col] = acc[mi][ni][r];           // plain store
          } else {
            atomicAdd(out + ((size_t)b * 2048 + mt * 128 + row) * 128 + col,
                      acc[mi][ni][r]);
          }
        }
      }
  }
}

// ---------------------------------------------------------------------------
// Reduce: out = sum over 8 ksp partial slices (zg pre-scaled by 1/128).
// ---------------------------------------------------------------------------
__global__ __launch_bounds__(256) void reduce_kernel(
    const float* __restrict__ partials, float* __restrict__ out)
{
  const size_t base = ((size_t)blockIdx.x * 256 + threadIdx.x) * 4;
  const float* p = partials + base;
  f32x4 s = *(const f32x4*)p;
  #pragma unroll
  for (int ksv = 1; ksv < 8; ++ksv) {
    f32x4 v = *(const f32x4*)(p + (size_t)ksv * 1048576);
    s.x += v.x; s.y += v.y; s.z += v.z; s.w += v.w;
  }
  *(f32x4*)(out + base) = s;
}

// ---------------------------------------------------------------------------
extern "C" void kernel_launch(void* const* d_in, const int* in_sizes, int n_in,
                              void* d_out, int out_size, void* d_ws, size_t ws_size,
                              hipStream_t stream) {
  const float* x_grid = (const float*)d_in[0];   // (4,128,128,2)
  const float* z_grid = (const float*)d_in[1];   // (4,128,128,128)
  const float* xt     = (const float*)d_in[2];   // (4,2048,2)
  const float* lsp    = (const float*)d_in[3];   // (2,)
  float* out = (float*)d_out;                    // (4,2048,128) f32

  char* ws = (char*)d_ws;
  unsigned short* zgb = (unsigned short*)ws;                   // 16 MB
  float* xg_trip = (float*)(ws + 16777216);                    // 768 KB
  float* xt4     = (float*)(ws + 16777216 + 786432);           // 128 KB
  const size_t poff = 16777216 + 786432 + 131072;              // 17694720
  const bool use_partials = ws_size >= poff + 33554432;        // +32 MB
  float* partials = use_partials ? (float*)(ws + poff) : nullptr;

  if (!use_partials)
    hipMemsetAsync(d_out, 0, (size_t)out_size * sizeof(float), stream);
  pre_kernel<<<1024, 256, 0, stream>>>(x_grid, z_grid, xt, lsp,
                                       zgb, xg_trip, xt4);
  main_kernel<<<512, 256, 0, stream>>>(zgb, xg_trip, xt4, out, partials);
  if (use_partials)
    reduce_kernel<<<1024, 256, 0, stream>>>(partials, out);
}